// Round 1
// baseline (177.723 us; speedup 1.0000x reference)
//
#include <hip/hip_runtime.h>

// MCLoss: mean |laplacian(gt) - laplacian(pr)|  ==  mean |laplacian(gt - pr)|
// (laplacian is linear). B=16, N=100000, M=9. nb[:,0]==i by construction.
//
// Strategy:
//   k1: d[(i*16+b)*3+c] = gt[b,i,c] - pr[b,i,c]   (transposed layout (N+1,16,3);
//       row N zeroed so idx==N gathers contribute 0; zero the accumulator)
//   k2: per (b,i): acc = d[i,b]*nn[i] - sum_j d[nb[i,j],b]; reduce |acc| -> atomicAdd
//       lane mapping b = tid&15  => the 16 lanes sharing i gather one contiguous
//       192B chunk per neighbor (coalesced gather).
//   k3: out = acc / (B*N*3)

#define NT 256

__global__ __launch_bounds__(NT) void k1_diff_transpose(
    const float* __restrict__ gt, const float* __restrict__ pr,
    float* __restrict__ d, float* __restrict__ acc, int N) {
  int u = blockIdx.x * NT + threadIdx.x;          // u = i*16 + b
  if (u < 16 * N) {
    int b = u & 15;
    int i = u >> 4;
    size_t src = ((size_t)b * N + i) * 3;
    float x = gt[src + 0] - pr[src + 0];
    float y = gt[src + 1] - pr[src + 1];
    float z = gt[src + 2] - pr[src + 2];
    size_t dst = (size_t)u * 3;                   // consecutive threads -> consecutive 12B
    d[dst + 0] = x; d[dst + 1] = y; d[dst + 2] = z;
  }
  if (blockIdx.x == 0) {
    if (threadIdx.x < 48) d[(size_t)N * 48 + threadIdx.x] = 0.0f;  // zero pad row
    if (threadIdx.x == 63) *acc = 0.0f;
  }
}

__global__ __launch_bounds__(NT) void k2_lap_loss(
    const float* __restrict__ d, const int* __restrict__ nb,
    const float* __restrict__ nn, float* __restrict__ acc, int N, int K) {
  int u = blockIdx.x * NT + threadIdx.x;
  float s = 0.0f;
  if (u < 16 * N) {
    int b3 = (u & 15) * 3;
    int i = u >> 4;
    float w = nn[i];                               // broadcast across 16 lanes
    const float* c = d + (size_t)u * 3;
    float ax = c[0] * w, ay = c[1] * w, az = c[2] * w;
    const int* row = nb + (size_t)i * (K + 1) + 1; // skip self (nb[i,0]==i)
    int idx[8];
#pragma unroll 8
    for (int j = 0; j < K; j++) idx[j] = row[j];
#pragma unroll 8
    for (int j = 0; j < K; j++) {
      const float* p = d + (size_t)idx[j] * 48 + b3;  // 16 lanes: contiguous 192B
      ax -= p[0]; ay -= p[1]; az -= p[2];
    }
    s = fabsf(ax) + fabsf(ay) + fabsf(az);
  }
  // wave (64-lane) reduction
#pragma unroll
  for (int off = 32; off > 0; off >>= 1) s += __shfl_down(s, off);
  __shared__ float sm[NT / 64];
  int lane = threadIdx.x & 63, wv = threadIdx.x >> 6;
  if (lane == 0) sm[wv] = s;
  __syncthreads();
  if (threadIdx.x == 0) {
    float t = 0.0f;
#pragma unroll
    for (int k = 0; k < NT / 64; k++) t += sm[k];
    atomicAdd(acc, t);
  }
}

__global__ void k3_finalize(const float* __restrict__ acc,
                            float* __restrict__ out, float scale) {
  if (threadIdx.x == 0) out[0] = acc[0] * scale;
}

// Fallback (workspace too small): gather directly from gt/pr, predicated on idx<N.
__global__ __launch_bounds__(NT) void k2_direct(
    const float* __restrict__ gt, const float* __restrict__ pr,
    const int* __restrict__ nb, const float* __restrict__ nn,
    float* __restrict__ acc, int N, int K) {
  int u = blockIdx.x * NT + threadIdx.x;
  float s = 0.0f;
  if (u < 16 * N) {
    int i = u & 0x7fffffff; // placeholder
    int b = u / N;
    i = u - b * N;
    size_t cidx = ((size_t)b * N + i) * 3;
    float w = nn[i];
    float ax = (gt[cidx] - pr[cidx]) * w;
    float ay = (gt[cidx + 1] - pr[cidx + 1]) * w;
    float az = (gt[cidx + 2] - pr[cidx + 2]) * w;
    const int* row = nb + (size_t)i * (K + 1) + 1;
#pragma unroll 8
    for (int j = 0; j < K; j++) {
      int idx = row[j];
      if (idx < N) {
        size_t p = ((size_t)b * N + idx) * 3;
        ax -= (gt[p] - pr[p]);
        ay -= (gt[p + 1] - pr[p + 1]);
        az -= (gt[p + 2] - pr[p + 2]);
      }
    }
    s = fabsf(ax) + fabsf(ay) + fabsf(az);
  }
#pragma unroll
  for (int off = 32; off > 0; off >>= 1) s += __shfl_down(s, off);
  __shared__ float sm[NT / 64];
  int lane = threadIdx.x & 63, wv = threadIdx.x >> 6;
  if (lane == 0) sm[wv] = s;
  __syncthreads();
  if (threadIdx.x == 0) {
    float t = 0.0f;
#pragma unroll
    for (int k = 0; k < NT / 64; k++) t += sm[k];
    atomicAdd(acc, t);
  }
}

__global__ void k0_zero(float* __restrict__ acc) {
  if (threadIdx.x == 0) *acc = 0.0f;
}

extern "C" void kernel_launch(void* const* d_in, const int* in_sizes, int n_in,
                              void* d_out, int out_size, void* d_ws, size_t ws_size,
                              hipStream_t stream) {
  const float* gt = (const float*)d_in[0];
  const float* pr = (const float*)d_in[1];
  const int*   nb = (const int*)d_in[2];
  const float* nn = (const float*)d_in[3];
  int N = in_sizes[3];                 // 100000
  int M = in_sizes[2] / N;             // 9
  int K = M - 1;                       // 8 neighbors
  // B is fixed at 16 by the problem (in_sizes[0] == 16*N*3).

  int total  = 16 * N;
  int blocks = (total + NT - 1) / NT;
  float scale = 1.0f / (16.0f * (float)N * 3.0f);

  size_t need = ((size_t)(N + 1) * 48 + 1) * sizeof(float);
  if (ws_size >= need) {
    float* d   = (float*)d_ws;
    float* acc = d + (size_t)(N + 1) * 48;
    k1_diff_transpose<<<blocks, NT, 0, stream>>>(gt, pr, d, acc, N);
    k2_lap_loss<<<blocks, NT, 0, stream>>>(d, nb, nn, acc, N, K);
    k3_finalize<<<1, 64, 0, stream>>>(acc, (float*)d_out, scale);
  } else {
    float* acc = (float*)d_ws;
    k0_zero<<<1, 64, 0, stream>>>(acc);
    k2_direct<<<blocks, NT, 0, stream>>>(gt, pr, nb, nn, acc, N, K);
    k3_finalize<<<1, 64, 0, stream>>>(acc, (float*)d_out, scale);
  }
}

// Round 2
// 130.395 us; speedup vs baseline: 1.3630x; 1.3630x over previous
//
#include <hip/hip_runtime.h>
#include <hip/hip_fp16.h>

// MCLoss: mean |lap(gt) - lap(pr)| == mean |lap(gt - pr)|  (laplacian linear).
// B=16, N=100000, M=9, nb[:,0]==i.
//
// k1: tiled (LDS) transpose+diff: d[i][b] = half4(gt[b,i]-pr[b,i], pad)
//     layout (N+1, 16) of 8B half4 -> gather row = 128B, 2 full cache lines.
//     Row N zeroed (absorbs idx==N), acc zeroed.
// k2: per thread: TWO i's x one b; 16+2 independent dwordx2 gathers in flight
//     (latency-bound kernel -> ILP). 16 lanes sharing i gather 128B contiguous.
// k3: out = acc / (B*N*3)

#define NT 256
#define TI 64   // i's per k1 block

union H4 {
  uint2 u;
  __half2 h[2];  // h[0]=(x,y) h[1]=(z,pad)
};

__global__ __launch_bounds__(NT) void k1_diff_pack(
    const float* __restrict__ gt, const float* __restrict__ pr,
    uint2* __restrict__ d, float* __restrict__ acc, int N) {
  __shared__ float sm[16][3 * TI + 1];   // +1 pad: phase-2 stride 193 (bank-friendly)
  const int t = threadIdx.x;
  const int i0 = blockIdx.x * TI;
  const int ni = min(TI, N - i0);        // valid i count in this tile
  const int nf = 3 * ni;

  // Phase 1: coalesced reads. 16 segments x 192 consecutive floats.
#pragma unroll
  for (int k = 0; k < (16 * 3 * TI) / NT; k++) {   // 12 iters
    int flat = t + k * NT;
    int b = flat / (3 * TI);
    int off = flat - b * (3 * TI);
    float v = 0.0f;
    if (off < nf) {
      size_t g = ((size_t)b * N + i0) * 3 + off;
      v = gt[g] - pr[g];
    }
    sm[b][off] = v;
  }
  __syncthreads();

  // Phase 2: coalesced 8B writes in transposed (i,b) order.
#pragma unroll
  for (int k = 0; k < (16 * TI) / NT; k++) {       // 4 iters
    int el = t + k * NT;
    int il = el >> 4;
    int b = el & 15;
    if (il < ni) {
      float x = sm[b][il * 3 + 0];
      float y = sm[b][il * 3 + 1];
      float z = sm[b][il * 3 + 2];
      H4 o;
      o.h[0] = __floats2half2_rn(x, y);
      o.h[1] = __floats2half2_rn(z, 0.0f);
      d[(size_t)(i0 + il) * 16 + b] = o.u;
    }
  }

  if (blockIdx.x == 0) {
    if (t < 16) { uint2 z; z.x = 0u; z.y = 0u; d[(size_t)N * 16 + t] = z; }
    if (t == 16) *acc = 0.0f;
  }
}

__device__ __forceinline__ void unpack(uint2 v, float& x, float& y, float& z) {
  H4 c; c.u = v;
  float2 xy = __half22float2(c.h[0]);
  x = xy.x; y = xy.y;
  z = __half2float(__low2half(c.h[1]));
}

__global__ __launch_bounds__(NT) void k2_lap_loss(
    const uint2* __restrict__ dp, const int* __restrict__ nb,
    const float* __restrict__ nn, float* __restrict__ acc, int N) {
  const int f = blockIdx.x * NT + threadIdx.x;
  const int g = f >> 4;
  const int b = f & 15;
  const int i0 = g * 2, i1 = i0 + 1;
  float s = 0.0f;

  if (i1 < N) {
    // --- issue ALL loads up front (18 independent dwordx2 gathers) ---
    const int* rA = nb + (size_t)i0 * 9 + 1;
    const int* rB = nb + (size_t)i1 * 9 + 1;
    int ia[8], ib[8];
#pragma unroll
    for (int j = 0; j < 8; j++) { ia[j] = rA[j]; ib[j] = rB[j]; }
    float wA = nn[i0], wB = nn[i1];
    uint2 cA = dp[(size_t)i0 * 16 + b];
    uint2 cB = dp[(size_t)i1 * 16 + b];
    uint2 vA[8], vB[8];
#pragma unroll
    for (int j = 0; j < 8; j++) vA[j] = dp[(size_t)ia[j] * 16 + b];
#pragma unroll
    for (int j = 0; j < 8; j++) vB[j] = dp[(size_t)ib[j] * 16 + b];

    float ax, ay, az;
    unpack(cA, ax, ay, az);
    ax *= wA; ay *= wA; az *= wA;
#pragma unroll
    for (int j = 0; j < 8; j++) {
      float x, y, z; unpack(vA[j], x, y, z);
      ax -= x; ay -= y; az -= z;
    }
    s = fabsf(ax) + fabsf(ay) + fabsf(az);

    float bx, by, bz;
    unpack(cB, bx, by, bz);
    bx *= wB; by *= wB; bz *= wB;
#pragma unroll
    for (int j = 0; j < 8; j++) {
      float x, y, z; unpack(vB[j], x, y, z);
      bx -= x; by -= y; bz -= z;
    }
    s += fabsf(bx) + fabsf(by) + fabsf(bz);
  } else if (i0 < N) {
    const int* rA = nb + (size_t)i0 * 9 + 1;
    int ia[8];
#pragma unroll
    for (int j = 0; j < 8; j++) ia[j] = rA[j];
    float wA = nn[i0];
    uint2 cA = dp[(size_t)i0 * 16 + b];
    uint2 vA[8];
#pragma unroll
    for (int j = 0; j < 8; j++) vA[j] = dp[(size_t)ia[j] * 16 + b];
    float ax, ay, az;
    unpack(cA, ax, ay, az);
    ax *= wA; ay *= wA; az *= wA;
#pragma unroll
    for (int j = 0; j < 8; j++) {
      float x, y, z; unpack(vA[j], x, y, z);
      ax -= x; ay -= y; az -= z;
    }
    s = fabsf(ax) + fabsf(ay) + fabsf(az);
  }

  // wave (64-lane) reduction, then block, then one atomic
#pragma unroll
  for (int off = 32; off > 0; off >>= 1) s += __shfl_down(s, off);
  __shared__ float sm[NT / 64];
  int lane = threadIdx.x & 63, wv = threadIdx.x >> 6;
  if (lane == 0) sm[wv] = s;
  __syncthreads();
  if (threadIdx.x == 0) {
    float tt = 0.0f;
#pragma unroll
    for (int k = 0; k < NT / 64; k++) tt += sm[k];
    atomicAdd(acc, tt);
  }
}

__global__ void k3_finalize(const float* __restrict__ acc,
                            float* __restrict__ out, float scale) {
  if (threadIdx.x == 0) out[0] = acc[0] * scale;
}

// ---------- fallback path (tiny ws or K != 8): direct fp32 gather ----------
__global__ void k0_zero(float* __restrict__ acc) {
  if (threadIdx.x == 0) *acc = 0.0f;
}

__global__ __launch_bounds__(NT) void k2_direct(
    const float* __restrict__ gt, const float* __restrict__ pr,
    const int* __restrict__ nb, const float* __restrict__ nn,
    float* __restrict__ acc, int N, int K) {
  int u = blockIdx.x * NT + threadIdx.x;
  float s = 0.0f;
  if (u < 16 * N) {
    int b = u / N;
    int i = u - b * N;
    size_t cidx = ((size_t)b * N + i) * 3;
    float w = nn[i];
    float ax = (gt[cidx] - pr[cidx]) * w;
    float ay = (gt[cidx + 1] - pr[cidx + 1]) * w;
    float az = (gt[cidx + 2] - pr[cidx + 2]) * w;
    const int* row = nb + (size_t)i * (K + 1) + 1;
    for (int j = 0; j < K; j++) {
      int idx = row[j];
      if (idx < N) {
        size_t p = ((size_t)b * N + idx) * 3;
        ax -= (gt[p] - pr[p]);
        ay -= (gt[p + 1] - pr[p + 1]);
        az -= (gt[p + 2] - pr[p + 2]);
      }
    }
    s = fabsf(ax) + fabsf(ay) + fabsf(az);
  }
#pragma unroll
  for (int off = 32; off > 0; off >>= 1) s += __shfl_down(s, off);
  __shared__ float sm[NT / 64];
  int lane = threadIdx.x & 63, wv = threadIdx.x >> 6;
  if (lane == 0) sm[wv] = s;
  __syncthreads();
  if (threadIdx.x == 0) {
    float tt = 0.0f;
#pragma unroll
    for (int k = 0; k < NT / 64; k++) tt += sm[k];
    atomicAdd(acc, tt);
  }
}

extern "C" void kernel_launch(void* const* d_in, const int* in_sizes, int n_in,
                              void* d_out, int out_size, void* d_ws, size_t ws_size,
                              hipStream_t stream) {
  const float* gt = (const float*)d_in[0];
  const float* pr = (const float*)d_in[1];
  const int*   nb = (const int*)d_in[2];
  const float* nn = (const float*)d_in[3];
  int N = in_sizes[3];           // 100000
  int M = in_sizes[2] / N;       // 9
  int K = M - 1;                 // 8

  float scale = 1.0f / (16.0f * (float)N * 3.0f);
  size_t need = (size_t)(N + 1) * 16 * sizeof(uint2) + 64;

  if (K == 8 && ws_size >= need) {
    uint2* d   = (uint2*)d_ws;
    float* acc = (float*)((char*)d_ws + (size_t)(N + 1) * 16 * sizeof(uint2));

    int b1 = (N + TI - 1) / TI;
    k1_diff_pack<<<b1, NT, 0, stream>>>(gt, pr, d, acc, N);

    int groups = (N + 1) / 2;
    int b2 = ((size_t)groups * 16 + NT - 1) / NT;
    k2_lap_loss<<<b2, NT, 0, stream>>>(d, nb, nn, acc, N);

    k3_finalize<<<1, 64, 0, stream>>>(acc, (float*)d_out, scale);
  } else {
    float* acc = (float*)d_ws;
    k0_zero<<<1, 64, 0, stream>>>(acc);
    int b2 = (16 * N + NT - 1) / NT;
    k2_direct<<<b2, NT, 0, stream>>>(gt, pr, nb, nn, acc, N, K);
    k3_finalize<<<1, 64, 0, stream>>>(acc, (float*)d_out, scale);
  }
}